// Round 3
// baseline (1401.321 us; speedup 1.0000x reference)
//
#include <hip/hip_runtime.h>
#include <hip/hip_bf16.h>
#include <math.h>

// Decoder: B=4096 T=5 V=8192 E=32 H=512 O=1024
// Pipeline: [prep: bf16 weights + x0] -> [embed GEMM+LN -> xs[1..4]] ->
//           [FUSED: 5x GRU + row-LN + FC, h resident in LDS] -> fp32 out
// NOTE: reference computes emb for t=0..4 but only t=0..3 feed the GRU -> we
// skip message[:,4,:] entirely (537MB instead of 671MB read).
// R1: k_embed = barrier-free streaming GEMM (split-K=4 over waves). WIN.
// R2: zero-LDS gru/fc FAILED (+248us): B-frag direct loads touch 16 scattered
//     lines/instr with no cross-wave reuse -> VMEM-latency-bound. Reverted.
// R3: GRU recurrence is ROW-LOCAL over batch => fuse 5xGRU+LN+FC into ONE
//     kernel. 128 blocks x 32 rows; h[32][512] bf16 lives in LDS across all
//     steps; Whh streamed L2->LDS once per block per step (1.5MB, shared
//     lines across blocks); gates in-register; in-place h update (disjoint
//     (row,j) per lane). Kills 4 h round-trips, 16x h re-staging, 64x Whh
//     over-read, 6 launch gaps. LDS 158.7KB, 1 block/CU.

#define LN_EPS 1e-5f

typedef __attribute__((ext_vector_type(8))) short bf8;   // 8 bf16 (4 VGPRs) — MFMA A/B frag
typedef __attribute__((ext_vector_type(4))) float fx4;   // 4 fp32 — MFMA C/D frag

__device__ __forceinline__ float bf2f(short s) {
    union { unsigned u; float f; } v;
    v.u = ((unsigned)(unsigned short)s) << 16;
    return v.f;
}
__device__ __forceinline__ short f2bf(float f) {
    union { __hip_bfloat16 h; unsigned short u; } v;
    v.h = __float2bfloat16(f);   // RNE
    return (short)v.u;
}
__device__ __forceinline__ float sigmoidf(float x) { return 1.0f / (1.0f + expf(-x)); }

// ---------------------------------------------------------------- k_prep
// Convert weights fp32->bf16, compute x0 = LN(init_emb)*g+b (bf16).
__global__ __launch_bounds__(256) void k_prep(
    const float* __restrict__ Whh, const float* __restrict__ Wih,
    const float* __restrict__ fcW, const float* __restrict__ embW,
    const float* __restrict__ init_emb, const float* __restrict__ eln_g,
    const float* __restrict__ eln_b,
    short* __restrict__ Whh_bf, short* __restrict__ Wih_bf,
    short* __restrict__ fcW_bf, short* __restrict__ embW_bf,
    short* __restrict__ x0v)
{
    int gid = blockIdx.x * blockDim.x + threadIdx.x;
    int stride = gridDim.x * blockDim.x;
    for (int i = gid; i < 1536 * 512; i += stride) Whh_bf[i] = f2bf(Whh[i]);
    for (int i = gid; i < 1536 * 32;  i += stride) Wih_bf[i] = f2bf(Wih[i]);
    for (int i = gid; i < 1024 * 512; i += stride) fcW_bf[i] = f2bf(fcW[i]);
    for (int i = gid; i < 32 * 8192;  i += stride) embW_bf[i] = f2bf(embW[i]);
    // x0 = LN(init_emb) — one 32-lane group
    if (blockIdx.x == 0 && threadIdx.x < 32) {
        float v = init_emb[threadIdx.x];
        float s = v, q = v * v;
        #pragma unroll
        for (int m = 1; m < 32; m <<= 1) { s += __shfl_xor(s, m); q += __shfl_xor(q, m); }
        float mean = s * (1.0f / 32.0f);
        float var  = q * (1.0f / 32.0f) - mean * mean;
        float rstd = rsqrtf(var + LN_EPS);
        x0v[threadIdx.x] = f2bf((v - mean) * rstd * eln_g[threadIdx.x] + eln_b[threadIdx.x]);
    }
}

// ---------------------------------------------------------------- k_embed
// C[16384,32] = message_rows(b,t<=3) @ embW^T, then LN over E=32 -> xs[t+1][b][:]
// Row index rg = b*4 + t. Block: 16 rows. 4 waves = 4 K-quarters (split-K),
// barrier-free main loop: A global->reg (fp32->bf16 in-reg), B direct bf8 loads.
__global__ __launch_bounds__(256) void k_embed(
    const float* __restrict__ msg, const short* __restrict__ embW_bf,
    const float* __restrict__ emb_b, const float* __restrict__ eln_g,
    const float* __restrict__ eln_b, short* __restrict__ xs)
{
    __shared__ float part[4][16][33];

    const int tid  = threadIdx.x;
    const int w    = tid >> 6;          // wave id = K-quarter
    const int lane = tid & 63;
    const int m    = lane & 15;
    const int quad = lane >> 4;

    const int rg = blockIdx.x * 16 + m;
    const int b  = rg >> 2, t = rg & 3;
    const float* __restrict__ row = msg + (size_t)(b * 5 + t) * 8192;

    const short* __restrict__ bw0 = embW_bf + (size_t)m * 8192;
    const short* __restrict__ bw1 = embW_bf + (size_t)(16 + m) * 8192;

    fx4 acc0, acc1;
    #pragma unroll
    for (int j = 0; j < 4; ++j) { acc0[j] = 0.0f; acc1[j] = 0.0f; }

    const int kbeg = w * 2048;
    const int kend = kbeg + 2048;
    #pragma unroll 4
    for (int k0 = kbeg; k0 < kend; k0 += 32) {
        const int kq = k0 + quad * 8;
        float4 a0 = *(const float4*)(row + kq);
        float4 a1 = *(const float4*)(row + kq + 4);
        bf8 a;
        a[0] = f2bf(a0.x); a[1] = f2bf(a0.y); a[2] = f2bf(a0.z); a[3] = f2bf(a0.w);
        a[4] = f2bf(a1.x); a[5] = f2bf(a1.y); a[6] = f2bf(a1.z); a[7] = f2bf(a1.w);
        bf8 b0 = *(const bf8*)(bw0 + kq);
        bf8 b1 = *(const bf8*)(bw1 + kq);
        acc0 = __builtin_amdgcn_mfma_f32_16x16x32_bf16(a, b0, acc0, 0, 0, 0);
        acc1 = __builtin_amdgcn_mfma_f32_16x16x32_bf16(a, b1, acc1, 0, 0, 0);
    }

    #pragma unroll
    for (int r = 0; r < 4; ++r) {
        part[w][quad * 4 + r][m]      = acc0[r];
        part[w][quad * 4 + r][16 + m] = acc1[r];
    }
    __syncthreads();

    {
        const int rr = tid >> 5;        // 0..7
        const int c  = tid & 31;
        #pragma unroll
        for (int half = 0; half < 2; ++half) {
            const int r = rr + half * 8;
            float v = part[0][r][c] + part[1][r][c] + part[2][r][c] + part[3][r][c]
                    + emb_b[c];
            float s = v, q = v * v;
            #pragma unroll
            for (int msk = 1; msk < 32; msk <<= 1) {
                s += __shfl_xor(s, msk); q += __shfl_xor(q, msk);
            }
            float mean = s * (1.0f / 32.0f);
            float var  = q * (1.0f / 32.0f) - mean * mean;
            float rstd = rsqrtf(var + LN_EPS);
            const int rg2 = blockIdx.x * 16 + r;
            const int b2 = rg2 >> 2, t2 = rg2 & 3;
            xs[(size_t)(t2 + 1) * 131072 + (size_t)b2 * 32 + c] =
                f2bf((v - mean) * rstd * eln_g[c] + eln_b[c]);
        }
    }
}

// ---------------------------------------------------------------- k_fused
// 5x GRU steps + row LN + FC for 32 batch rows per block. 512 thr = 8 waves.
// h[32][512] bf16 resident in LDS. Per step: stream Whh (1536x512) through
// Bs in 16 BK=32 chunks (+1 Wih chunk); wave w owns j-slice [w*64, w*64+64).
// acc[0]=r, acc[1]=z accumulate x+h parts; acc[2]=h@Whh_n; acc_ni=x@Wih_n.
// In-place h update: lane reads/writes its own (row,j) — disjoint across waves.
__global__ __launch_bounds__(512, 2) void k_fused(
    const short* __restrict__ xs, const short* __restrict__ x0v,
    const short* __restrict__ Whh_bf, const short* __restrict__ Wih_bf,
    const float* __restrict__ bih, const float* __restrict__ bhh,
    const float* __restrict__ gln_g, const float* __restrict__ gln_b,
    const short* __restrict__ fcW_bf, const float* __restrict__ fc_b,
    float* __restrict__ out)
{
    __shared__ short Hs[32][520];    // h state, stride 1040B (16B-mult, 2-way banks)
    __shared__ short Bs[1536][40];   // weight tile, stride 80B (16B-mult, 2-way banks)
    __shared__ short Xs[32][40];     // x_t tile

    const int tid  = threadIdx.x;
    const int wid  = tid >> 6;       // 0..7
    const int lane = tid & 63;
    const int m    = lane & 15;
    const int quad = lane >> 4;
    const int row0 = blockIdx.x * 32;
    const int jw   = wid * 64;       // GRU j-slice base for this wave

    // zero h state
    {
        int* hz = (int*)&Hs[0][0];
        for (int i = tid; i < 32 * 520 / 2; i += 512) hz[i] = 0;
    }

    // hoist gate biases for this lane's j columns (fixed across steps)
    float bb_r[4], bb_z[4], b_in[4], b_hn[4];
    #pragma unroll
    for (int ct = 0; ct < 4; ++ct) {
        int j = jw + ct * 16 + m;
        bb_r[ct] = bih[j] + bhh[j];
        bb_z[ct] = bih[512 + j] + bhh[512 + j];
        b_in[ct] = bih[1024 + j];
        b_hn[ct] = bhh[1024 + j];
    }

    for (int t = 0; t < 5; ++t) {
        const short* xp = (t == 0) ? x0v : xs + (size_t)t * 131072;
        const int xstride = (t == 0) ? 0 : 32;

        fx4 acc[3][2][4];    // [gate r/z/nh][rowtile][coltile]
        fx4 acc_ni[2][4];
        #pragma unroll
        for (int s = 0; s < 3; ++s)
            #pragma unroll
            for (int rt = 0; rt < 2; ++rt)
                #pragma unroll
                for (int ct = 0; ct < 4; ++ct)
                    #pragma unroll
                    for (int q = 0; q < 4; ++q) acc[s][rt][ct][q] = 0.0f;
        #pragma unroll
        for (int rt = 0; rt < 2; ++rt)
            #pragma unroll
            for (int ct = 0; ct < 4; ++ct)
                #pragma unroll
                for (int q = 0; q < 4; ++q) acc_ni[rt][ct][q] = 0.0f;

        // 17 chunks: ch<16 from Whh (BK=32), ch==16 from Wih (K=32)
        for (int ch = 0; ch < 17; ++ch) {
            if (ch < 16) {
                const int k0 = ch * 32;
                #pragma unroll
                for (int it = 0; it < 12; ++it) {        // 6144 bf8-chunks
                    int c = tid + it * 512;
                    int r = c >> 2, kp = (c & 3) * 8;
                    *(bf8*)&Bs[r][kp] = *(const bf8*)(Whh_bf + (size_t)r * 512 + k0 + kp);
                }
                if (ch == 0 && tid < 128) {              // stage x_t (32x32)
                    int r = tid >> 2, kp = (tid & 3) * 8;
                    *(bf8*)&Xs[r][kp] = *(const bf8*)(xp + (size_t)(row0 + r) * xstride + kp);
                }
            } else {
                #pragma unroll
                for (int it = 0; it < 12; ++it) {
                    int c = tid + it * 512;
                    int r = c >> 2, kp = (c & 3) * 8;
                    *(bf8*)&Bs[r][kp] = *(const bf8*)(Wih_bf + (size_t)r * 32 + kp);
                }
            }
            __syncthreads();
            if (ch < 16) {
                const int k0 = ch * 32;
                bf8 a[2];
                #pragma unroll
                for (int rt = 0; rt < 2; ++rt)
                    a[rt] = *(const bf8*)&Hs[rt * 16 + m][k0 + quad * 8];
                #pragma unroll
                for (int s = 0; s < 3; ++s)
                    #pragma unroll
                    for (int ct = 0; ct < 4; ++ct) {
                        bf8 b = *(const bf8*)&Bs[s * 512 + jw + ct * 16 + m][quad * 8];
                        #pragma unroll
                        for (int rt = 0; rt < 2; ++rt)
                            acc[s][rt][ct] = __builtin_amdgcn_mfma_f32_16x16x32_bf16(
                                a[rt], b, acc[s][rt][ct], 0, 0, 0);
                    }
            } else {
                bf8 a[2];
                #pragma unroll
                for (int rt = 0; rt < 2; ++rt)
                    a[rt] = *(const bf8*)&Xs[rt * 16 + m][quad * 8];
                #pragma unroll
                for (int s = 0; s < 3; ++s)
                    #pragma unroll
                    for (int ct = 0; ct < 4; ++ct) {
                        bf8 b = *(const bf8*)&Bs[s * 512 + jw + ct * 16 + m][quad * 8];
                        #pragma unroll
                        for (int rt = 0; rt < 2; ++rt) {
                            if (s < 2)
                                acc[s][rt][ct] = __builtin_amdgcn_mfma_f32_16x16x32_bf16(
                                    a[rt], b, acc[s][rt][ct], 0, 0, 0);
                            else
                                acc_ni[rt][ct] = __builtin_amdgcn_mfma_f32_16x16x32_bf16(
                                    a[rt], b, acc_ni[rt][ct], 0, 0, 0);
                        }
                    }
            }
            __syncthreads();
        }

        // gates + in-place h update (each lane RMWs only its own (row,j))
        #pragma unroll
        for (int rt = 0; rt < 2; ++rt)
            #pragma unroll
            for (int ct = 0; ct < 4; ++ct) {
                int j = jw + ct * 16 + m;
                #pragma unroll
                for (int rr = 0; rr < 4; ++rr) {
                    int row = rt * 16 + quad * 4 + rr;
                    float rr_ = sigmoidf(acc[0][rt][ct][rr] + bb_r[ct]);
                    float zz  = sigmoidf(acc[1][rt][ct][rr] + bb_z[ct]);
                    float hn  = acc[2][rt][ct][rr] + b_hn[ct];
                    float nn  = tanhf(acc_ni[rt][ct][rr] + b_in[ct] + rr_ * hn);
                    float ho  = bf2f(Hs[row][j]);
                    Hs[row][j] = f2bf((1.0f - zz) * nn + zz * ho);
                }
            }
        __syncthreads();
    }

    // ---- row LN (4 rows per wave), in-place in Hs ----
    #pragma unroll
    for (int i = 0; i < 4; ++i) {
        int row = wid * 4 + i;
        bf8 v = *(const bf8*)&Hs[row][lane * 8];
        float f[8]; float sum = 0.f, sq = 0.f;
        #pragma unroll
        for (int e = 0; e < 8; ++e) { f[e] = bf2f(v[e]); sum += f[e]; sq += f[e] * f[e]; }
        #pragma unroll
        for (int msk = 1; msk < 64; msk <<= 1) { sum += __shfl_xor(sum, msk); sq += __shfl_xor(sq, msk); }
        float mean = sum * (1.0f / 512.0f);
        float var  = sq * (1.0f / 512.0f) - mean * mean;
        float rstd = rsqrtf(var + LN_EPS);
        short o[8];
        #pragma unroll
        for (int e = 0; e < 8; ++e) {
            int col = lane * 8 + e;
            o[e] = f2bf((f[e] - mean) * rstd * gln_g[col] + gln_b[col]);
        }
        *(bf8*)&Hs[row][lane * 8] = *(bf8*)o;
    }
    __syncthreads();

    // ---- FC: out[32 rows x 1024] = sigmoid(hln @ fcW^T + b); wave owns 128 cols
    float fcb[8];
    #pragma unroll
    for (int ct = 0; ct < 8; ++ct) fcb[ct] = fc_b[wid * 128 + ct * 16 + m];

    fx4 facc[2][8];
    #pragma unroll
    for (int rt = 0; rt < 2; ++rt)
        #pragma unroll
        for (int ct = 0; ct < 8; ++ct)
            #pragma unroll
            for (int q = 0; q < 4; ++q) facc[rt][ct][q] = 0.0f;

    for (int ch = 0; ch < 16; ++ch) {
        const int k0 = ch * 32;
        #pragma unroll
        for (int it = 0; it < 8; ++it) {        // 4096 bf8-chunks (1024 rows x 4)
            int c = tid + it * 512;
            int r = c >> 2, kp = (c & 3) * 8;
            *(bf8*)&Bs[r][kp] = *(const bf8*)(fcW_bf + (size_t)r * 512 + k0 + kp);
        }
        __syncthreads();
        bf8 a[2];
        #pragma unroll
        for (int rt = 0; rt < 2; ++rt)
            a[rt] = *(const bf8*)&Hs[rt * 16 + m][k0 + quad * 8];
        #pragma unroll
        for (int ct = 0; ct < 8; ++ct) {
            bf8 b = *(const bf8*)&Bs[wid * 128 + ct * 16 + m][quad * 8];
            #pragma unroll
            for (int rt = 0; rt < 2; ++rt)
                facc[rt][ct] = __builtin_amdgcn_mfma_f32_16x16x32_bf16(
                    a[rt], b, facc[rt][ct], 0, 0, 0);
        }
        __syncthreads();
    }

    #pragma unroll
    for (int rt = 0; rt < 2; ++rt)
        #pragma unroll
        for (int ct = 0; ct < 8; ++ct) {
            int col = wid * 128 + ct * 16 + m;
            #pragma unroll
            for (int rr = 0; rr < 4; ++rr) {
                int row = row0 + rt * 16 + quad * 4 + rr;
                out[(size_t)row * 1024 + col] = sigmoidf(facc[rt][ct][rr] + fcb[ct]);
            }
        }
}

// ---------------------------------------------------------------- launcher
extern "C" void kernel_launch(void* const* d_in, const int* in_sizes, int n_in,
                              void* d_out, int out_size, void* d_ws, size_t ws_size,
                              hipStream_t stream)
{
    const float* msg      = (const float*)d_in[0];
    const float* embW     = (const float*)d_in[1];
    const float* emb_b    = (const float*)d_in[2];
    const float* init_emb = (const float*)d_in[3];
    const float* eln_g    = (const float*)d_in[4];
    const float* eln_b    = (const float*)d_in[5];
    const float* Wih      = (const float*)d_in[6];
    const float* Whh      = (const float*)d_in[7];
    const float* bih      = (const float*)d_in[8];
    const float* bhh      = (const float*)d_in[9];
    const float* gln_g    = (const float*)d_in[10];
    const float* gln_b    = (const float*)d_in[11];
    const float* fcW      = (const float*)d_in[12];
    const float* fc_b     = (const float*)d_in[13];
    float* out = (float*)d_out;

    // ws carve-out (shorts). Total ~4.6 MB.
    short* base    = (short*)d_ws;
    short* Whh_bf  = base;                        // 1536*512 = 786432
    short* Wih_bf  = Whh_bf + 1536 * 512;         // 1536*32  = 49152
    short* fcW_bf  = Wih_bf + 1536 * 32;          // 1024*512 = 524288
    short* embW_bf = fcW_bf + 1024 * 512;         // 32*8192  = 262144
    short* xs      = embW_bf + 32 * 8192;         // 5*4096*32 = 655360 (slot 0 unused)
    short* x0v     = xs + 5 * 4096 * 32;          // 32

    k_prep<<<512, 256, 0, stream>>>(Whh, Wih, fcW, embW, init_emb, eln_g, eln_b,
                                    Whh_bf, Wih_bf, fcW_bf, embW_bf, x0v);
    k_embed<<<1024, 256, 0, stream>>>(msg, embW_bf, emb_b, eln_g, eln_b, xs);
    k_fused<<<128, 512, 0, stream>>>(xs, x0v, Whh_bf, Wih_bf, bih, bhh,
                                     gln_g, gln_b, fcW_bf, fc_b, out);
}

// Round 7
// 983.528 us; speedup vs baseline: 1.4248x; 1.4248x over previous
//
#include <hip/hip_runtime.h>
#include <hip/hip_bf16.h>
#include <math.h>

// Decoder: B=4096 T=5 V=8192 E=32 H=512 O=1024
// R1: k_embed = barrier-free streaming GEMM (split-K=4 over waves). WIN.
// R2: zero-LDS gru/fc with NAIVE layout FAILED: each B-load touched 16
//     scattered cache lines. Layout problem, not pattern problem.
// R3: monolithic fused kernel FAILED (548us, MfmaUtil 2.8%, Occ 12%):
//     128 blocks = half machine idle; 96 barrier-drained 96KB LDS stages
//     at 1 block/CU; 496MB HBM refetch.
// R4: weights pre-packed in MFMA-FRAGMENT ORDER (tile = 16 cols x 32 k,
//     lane l owns 16B at tile_base + l*16) -> a wave's B-fragment is ONE
//     coalesced 1KB load, global->reg, zero LDS, zero barriers in the
//     K-stream. h[16][512] lives in LDS (17KB); 2 barriers per GRU step.
//     256 blocks x 16 rows x 8 waves (wave owns 64 j-cols). LN+FC fused,
//     fcW fragment-packed too.
// R5/R6/R7: identical resubmits of R4 (rounds died on GPU acquisition
//     timeout — no measurement has ever been taken for this design).

#define LN_EPS 1e-5f

typedef __attribute__((ext_vector_type(8))) short bf8;   // 8 bf16 (4 VGPRs) — MFMA A/B frag
typedef __attribute__((ext_vector_type(4))) float fx4;   // 4 fp32 — MFMA C/D frag

__device__ __forceinline__ float bf2f(short s) {
    union { unsigned u; float f; } v;
    v.u = ((unsigned)(unsigned short)s) << 16;
    return v.f;
}
__device__ __forceinline__ short f2bf(float f) {
    union { __hip_bfloat16 h; unsigned short u; } v;
    v.h = __float2bfloat16(f);   // RNE
    return (short)v.u;
}
__device__ __forceinline__ float sigmoidf(float x) { return 1.0f / (1.0f + expf(-x)); }

// ---------------------------------------------------------------- k_prep
// fp32->bf16 weight packing. Whh/Wih/fcW go to MFMA-fragment order:
//   tile (g_tile, k_tile) covers rows [g_tile*16, +16) x k [k_tile*32, +32);
//   flat = (g_tile*NKT + k_tile)*512 + lane*8 + e, where lane=(quad*16+m):
//   src_row = g_tile*16 + (lane&15), src_k = k_tile*32 + (lane>>4)*8 + e.
// embW stays row-major bf16 (k_embed reads it row-streamed).
__global__ __launch_bounds__(256) void k_prep(
    const float* __restrict__ Whh, const float* __restrict__ Wih,
    const float* __restrict__ fcW, const float* __restrict__ embW,
    const float* __restrict__ init_emb, const float* __restrict__ eln_g,
    const float* __restrict__ eln_b,
    short* __restrict__ Whh_pk, short* __restrict__ Wih_pk,
    short* __restrict__ fcW_pk, short* __restrict__ embW_bf,
    short* __restrict__ x0v)
{
    int gid = blockIdx.x * blockDim.x + threadIdx.x;
    int stride = gridDim.x * blockDim.x;
    // Whh: 1536x512, 96 g_tiles x 16 k_tiles
    for (int i = gid; i < 1536 * 512; i += stride) {
        int tile = i >> 9, l = (i >> 3) & 63, e = i & 7;
        int gt = tile >> 4, kt = tile & 15;
        int row = gt * 16 + (l & 15);
        int k   = kt * 32 + (l >> 4) * 8 + e;
        Whh_pk[i] = f2bf(Whh[(size_t)row * 512 + k]);
    }
    // Wih: 1536x32, 96 g_tiles x 1 k_tile
    for (int i = gid; i < 96 * 512; i += stride) {
        int gt = i >> 9, l = (i >> 3) & 63, e = i & 7;
        int row = gt * 16 + (l & 15);
        int k   = (l >> 4) * 8 + e;
        Wih_pk[i] = f2bf(Wih[(size_t)row * 32 + k]);
    }
    // fcW: 1024x512, 64 g_tiles x 16 k_tiles
    for (int i = gid; i < 1024 * 512; i += stride) {
        int tile = i >> 9, l = (i >> 3) & 63, e = i & 7;
        int gt = tile >> 4, kt = tile & 15;
        int row = gt * 16 + (l & 15);
        int k   = kt * 32 + (l >> 4) * 8 + e;
        fcW_pk[i] = f2bf(fcW[(size_t)row * 512 + k]);
    }
    for (int i = gid; i < 32 * 8192;  i += stride) embW_bf[i] = f2bf(embW[i]);
    // x0 = LN(init_emb) — one 32-lane group
    if (blockIdx.x == 0 && threadIdx.x < 32) {
        float v = init_emb[threadIdx.x];
        float s = v, q = v * v;
        #pragma unroll
        for (int m = 1; m < 32; m <<= 1) { s += __shfl_xor(s, m); q += __shfl_xor(q, m); }
        float mean = s * (1.0f / 32.0f);
        float var  = q * (1.0f / 32.0f) - mean * mean;
        float rstd = rsqrtf(var + LN_EPS);
        x0v[threadIdx.x] = f2bf((v - mean) * rstd * eln_g[threadIdx.x] + eln_b[threadIdx.x]);
    }
}

// ---------------------------------------------------------------- k_embed
// C[16384,32] = message_rows(b,t<=3) @ embW^T, then LN over E=32 -> xs[t+1][b][:]
// (unchanged from R1 — proven, ~HBM-bound at its 85us floor)
__global__ __launch_bounds__(256) void k_embed(
    const float* __restrict__ msg, const short* __restrict__ embW_bf,
    const float* __restrict__ emb_b, const float* __restrict__ eln_g,
    const float* __restrict__ eln_b, short* __restrict__ xs)
{
    __shared__ float part[4][16][33];

    const int tid  = threadIdx.x;
    const int w    = tid >> 6;          // wave id = K-quarter
    const int lane = tid & 63;
    const int m    = lane & 15;
    const int quad = lane >> 4;

    const int rg = blockIdx.x * 16 + m;
    const int b  = rg >> 2, t = rg & 3;
    const float* __restrict__ row = msg + (size_t)(b * 5 + t) * 8192;

    const short* __restrict__ bw0 = embW_bf + (size_t)m * 8192;
    const short* __restrict__ bw1 = embW_bf + (size_t)(16 + m) * 8192;

    fx4 acc0, acc1;
    #pragma unroll
    for (int j = 0; j < 4; ++j) { acc0[j] = 0.0f; acc1[j] = 0.0f; }

    const int kbeg = w * 2048;
    const int kend = kbeg + 2048;
    #pragma unroll 4
    for (int k0 = kbeg; k0 < kend; k0 += 32) {
        const int kq = k0 + quad * 8;
        float4 a0 = *(const float4*)(row + kq);
        float4 a1 = *(const float4*)(row + kq + 4);
        bf8 a;
        a[0] = f2bf(a0.x); a[1] = f2bf(a0.y); a[2] = f2bf(a0.z); a[3] = f2bf(a0.w);
        a[4] = f2bf(a1.x); a[5] = f2bf(a1.y); a[6] = f2bf(a1.z); a[7] = f2bf(a1.w);
        bf8 b0 = *(const bf8*)(bw0 + kq);
        bf8 b1 = *(const bf8*)(bw1 + kq);
        acc0 = __builtin_amdgcn_mfma_f32_16x16x32_bf16(a, b0, acc0, 0, 0, 0);
        acc1 = __builtin_amdgcn_mfma_f32_16x16x32_bf16(a, b1, acc1, 0, 0, 0);
    }

    #pragma unroll
    for (int r = 0; r < 4; ++r) {
        part[w][quad * 4 + r][m]      = acc0[r];
        part[w][quad * 4 + r][16 + m] = acc1[r];
    }
    __syncthreads();

    {
        const int rr = tid >> 5;        // 0..7
        const int c  = tid & 31;
        #pragma unroll
        for (int half = 0; half < 2; ++half) {
            const int r = rr + half * 8;
            float v = part[0][r][c] + part[1][r][c] + part[2][r][c] + part[3][r][c]
                    + emb_b[c];
            float s = v, q = v * v;
            #pragma unroll
            for (int msk = 1; msk < 32; msk <<= 1) {
                s += __shfl_xor(s, msk); q += __shfl_xor(q, msk);
            }
            float mean = s * (1.0f / 32.0f);
            float var  = q * (1.0f / 32.0f) - mean * mean;
            float rstd = rsqrtf(var + LN_EPS);
            const int rg2 = blockIdx.x * 16 + r;
            const int b2 = rg2 >> 2, t2 = rg2 & 3;
            xs[(size_t)(t2 + 1) * 131072 + (size_t)b2 * 32 + c] =
                f2bf((v - mean) * rstd * eln_g[c] + eln_b[c]);
        }
    }
}

// ---------------------------------------------------------------- k_fused
// 5x GRU + row-LN + FC for 16 batch rows per block. 256 blocks, 512 thr.
// h[16][512] bf16 in LDS. Wave w owns j-slice [w*64, w*64+64).
// Per step: 16 chunks, each = 1 LDS A-frag read + 12 coalesced 1KB B-frag
// loads (fragment-packed Whh) + 12 MFMA — NO barriers in the stream.
// Then 1 x-chunk (Wih_pk), then barrier -> gates -> in-place h -> barrier.
__global__ __launch_bounds__(512, 2) void k_fused(
    const short* __restrict__ xs, const short* __restrict__ x0v,
    const short* __restrict__ Whh_pk, const short* __restrict__ Wih_pk,
    const float* __restrict__ bih, const float* __restrict__ bhh,
    const float* __restrict__ gln_g, const float* __restrict__ gln_b,
    const short* __restrict__ fcW_pk, const float* __restrict__ fc_b,
    float* __restrict__ out)
{
    __shared__ short Hs[16][520];    // h state; row stride 1040B

    const int tid  = threadIdx.x;
    const int wid  = tid >> 6;       // 0..7
    const int lane = tid & 63;
    const int m    = lane & 15;
    const int quad = lane >> 4;
    const int row0 = blockIdx.x * 16;
    const int jw   = wid * 64;       // GRU j-slice base for this wave

    // zero h state
    {
        int* hz = (int*)&Hs[0][0];
        for (int i = tid; i < 16 * 520 / 2; i += 512) hz[i] = 0;
    }

    // hoist gate biases for this lane's j columns
    float bb_r[4], bb_z[4], b_in[4], b_hn[4];
    #pragma unroll
    for (int ct = 0; ct < 4; ++ct) {
        int j = jw + ct * 16 + m;
        bb_r[ct] = bih[j] + bhh[j];
        bb_z[ct] = bih[512 + j] + bhh[512 + j];
        b_in[ct] = bih[1024 + j];
        b_hn[ct] = bhh[1024 + j];
    }

    // fragment-packed base pointers for this wave/lane
    // Whh_pk tile(s,ct,ch) offset = ((s*32 + wid*4 + ct)*16 + ch)*512 + lane*8
    const short* __restrict__ base_w = Whh_pk + (size_t)(wid * 4 * 16) * 512 + lane * 8;
    const short* __restrict__ base_i = Wih_pk + (size_t)(wid * 4) * 512 + lane * 8;

    __syncthreads();

    for (int t = 0; t < 5; ++t) {
        const short* xp = (t == 0) ? x0v : xs + (size_t)t * 131072 + (size_t)row0 * 32;
        const int xstride = (t == 0) ? 0 : 32;
        bf8 xa = *(const bf8*)(xp + (size_t)m * xstride + quad * 8);

        fx4 acc_r[4], acc_z[4], acc_hn[4], acc_ni[4];
        #pragma unroll
        for (int ct = 0; ct < 4; ++ct)
            #pragma unroll
            for (int q = 0; q < 4; ++q) {
                acc_r[ct][q] = 0.0f; acc_z[ct][q] = 0.0f;
                acc_hn[ct][q] = 0.0f; acc_ni[ct][q] = 0.0f;
            }

        // h @ Whh^T: 16 chunks, barrier-free
        #pragma unroll 4
        for (int ch = 0; ch < 16; ++ch) {
            bf8 a = *(const bf8*)&Hs[m][ch * 32 + quad * 8];
            #pragma unroll
            for (int ct = 0; ct < 4; ++ct) {
                bf8 br = *(const bf8*)(base_w + (size_t)(0 * 262144 + ct * 8192 + ch * 512));
                bf8 bz = *(const bf8*)(base_w + (size_t)(1 * 262144 + ct * 8192 + ch * 512));
                bf8 bn = *(const bf8*)(base_w + (size_t)(2 * 262144 + ct * 8192 + ch * 512));
                acc_r[ct]  = __builtin_amdgcn_mfma_f32_16x16x32_bf16(a, br, acc_r[ct], 0, 0, 0);
                acc_z[ct]  = __builtin_amdgcn_mfma_f32_16x16x32_bf16(a, bz, acc_z[ct], 0, 0, 0);
                acc_hn[ct] = __builtin_amdgcn_mfma_f32_16x16x32_bf16(a, bn, acc_hn[ct], 0, 0, 0);
            }
        }
        // x @ Wih^T: single K=32 chunk
        #pragma unroll
        for (int ct = 0; ct < 4; ++ct) {
            bf8 br = *(const bf8*)(base_i + (size_t)(0 * 16384 + ct * 512));
            bf8 bz = *(const bf8*)(base_i + (size_t)(1 * 16384 + ct * 512));
            bf8 bn = *(const bf8*)(base_i + (size_t)(2 * 16384 + ct * 512));
            acc_r[ct]  = __builtin_amdgcn_mfma_f32_16x16x32_bf16(xa, br, acc_r[ct], 0, 0, 0);
            acc_z[ct]  = __builtin_amdgcn_mfma_f32_16x16x32_bf16(xa, bz, acc_z[ct], 0, 0, 0);
            acc_ni[ct] = __builtin_amdgcn_mfma_f32_16x16x32_bf16(xa, bn, acc_ni[ct], 0, 0, 0);
        }

        __syncthreads();   // all waves done reading Hs for this step

        // gates + in-place h update (lane owns (quad*4+rr, jw+ct*16+m))
        #pragma unroll
        for (int ct = 0; ct < 4; ++ct) {
            int j = jw + ct * 16 + m;
            #pragma unroll
            for (int rr = 0; rr < 4; ++rr) {
                int row = quad * 4 + rr;
                float rr_ = sigmoidf(acc_r[ct][rr] + bb_r[ct]);
                float zz  = sigmoidf(acc_z[ct][rr] + bb_z[ct]);
                float hn  = acc_hn[ct][rr] + b_hn[ct];
                float nn  = tanhf(acc_ni[ct][rr] + b_in[ct] + rr_ * hn);
                float ho  = bf2f(Hs[row][j]);
                Hs[row][j] = f2bf((1.0f - zz) * nn + zz * ho);
            }
        }
        __syncthreads();
    }

    // ---- row LN (2 rows per wave), in-place in Hs ----
    #pragma unroll
    for (int i = 0; i < 2; ++i) {
        int row = wid * 2 + i;
        bf8 v = *(const bf8*)&Hs[row][lane * 8];
        float f[8]; float sum = 0.f, sq = 0.f;
        #pragma unroll
        for (int e = 0; e < 8; ++e) { f[e] = bf2f(v[e]); sum += f[e]; sq += f[e] * f[e]; }
        #pragma unroll
        for (int msk = 1; msk < 64; msk <<= 1) { sum += __shfl_xor(sum, msk); sq += __shfl_xor(sq, msk); }
        float mean = sum * (1.0f / 512.0f);
        float var  = sq * (1.0f / 512.0f) - mean * mean;
        float rstd = rsqrtf(var + LN_EPS);
        short o[8];
        #pragma unroll
        for (int e = 0; e < 8; ++e) {
            int col = lane * 8 + e;
            o[e] = f2bf((f[e] - mean) * rstd * gln_g[col] + gln_b[col]);
        }
        *(bf8*)&Hs[row][lane * 8] = *(bf8*)o;
    }
    __syncthreads();

    // ---- FC: out[16 x 1024] = sigmoid(hln @ fcW^T + b); wave owns 128 cols
    const short* __restrict__ base_f = fcW_pk + (size_t)(wid * 8 * 16) * 512 + lane * 8;
    float fcb[8];
    #pragma unroll
    for (int ct = 0; ct < 8; ++ct) fcb[ct] = fc_b[wid * 128 + ct * 16 + m];

    fx4 facc[8];
    #pragma unroll
    for (int ct = 0; ct < 8; ++ct)
        #pragma unroll
        for (int q = 0; q < 4; ++q) facc[ct][q] = 0.0f;

    #pragma unroll 4
    for (int ch = 0; ch < 16; ++ch) {
        bf8 a = *(const bf8*)&Hs[m][ch * 32 + quad * 8];
        #pragma unroll
        for (int ct = 0; ct < 8; ++ct) {
            bf8 b = *(const bf8*)(base_f + (size_t)(ct * 8192 + ch * 512));
            facc[ct] = __builtin_amdgcn_mfma_f32_16x16x32_bf16(a, b, facc[ct], 0, 0, 0);
        }
    }

    #pragma unroll
    for (int ct = 0; ct < 8; ++ct) {
        int col = wid * 128 + ct * 16 + m;
        #pragma unroll
        for (int rr = 0; rr < 4; ++rr) {
            int row = row0 + quad * 4 + rr;
            out[(size_t)row * 1024 + col] = sigmoidf(facc[ct][rr] + fcb[ct]);
        }
    }
}

// ---------------------------------------------------------------- launcher
extern "C" void kernel_launch(void* const* d_in, const int* in_sizes, int n_in,
                              void* d_out, int out_size, void* d_ws, size_t ws_size,
                              hipStream_t stream)
{
    const float* msg      = (const float*)d_in[0];
    const float* embW     = (const float*)d_in[1];
    const float* emb_b    = (const float*)d_in[2];
    const float* init_emb = (const float*)d_in[3];
    const float* eln_g    = (const float*)d_in[4];
    const float* eln_b    = (const float*)d_in[5];
    const float* Wih      = (const float*)d_in[6];
    const float* Whh      = (const float*)d_in[7];
    const float* bih      = (const float*)d_in[8];
    const float* bhh      = (const float*)d_in[9];
    const float* gln_g    = (const float*)d_in[10];
    const float* gln_b    = (const float*)d_in[11];
    const float* fcW      = (const float*)d_in[12];
    const float* fc_b     = (const float*)d_in[13];
    float* out = (float*)d_out;

    // ws carve-out (shorts). Total ~4.6 MB.
    short* base    = (short*)d_ws;
    short* Whh_pk  = base;                        // 1536*512 = 786432
    short* Wih_pk  = Whh_pk + 1536 * 512;         // 96*512   = 49152
    short* fcW_pk  = Wih_pk + 96 * 512;           // 1024*512 = 524288
    short* embW_bf = fcW_pk + 1024 * 512;         // 32*8192  = 262144
    short* xs      = embW_bf + 32 * 8192;         // 5*4096*32 = 655360 (slot 0 unused)
    short* x0v     = xs + 5 * 4096 * 32;          // 32

    k_prep<<<512, 256, 0, stream>>>(Whh, Wih, fcW, embW, init_emb, eln_g, eln_b,
                                    Whh_pk, Wih_pk, fcW_pk, embW_bf, x0v);
    k_embed<<<1024, 256, 0, stream>>>(msg, embW_bf, emb_b, eln_g, eln_b, xs);
    k_fused<<<256, 512, 0, stream>>>(xs, x0v, Whh_pk, Wih_pk, bih, bhh,
                                     gln_g, gln_b, fcW_pk, fc_b, out);
}